// Round 8
// baseline (304.821 us; speedup 1.0000x reference)
//
#include <hip/hip_runtime.h>

#define BH_ 32
#define S_ 2048
#define D_ 64
#define DQK 128
#define BQ 128   // q rows per block (4 waves x 32 q-rows each)

typedef unsigned short u16;
typedef u16 u16x4 __attribute__((ext_vector_type(4)));
typedef u16 u16x8 __attribute__((ext_vector_type(8)));
typedef __bf16 bf16x8 __attribute__((ext_vector_type(8)));
typedef float f32x4 __attribute__((ext_vector_type(4)));

__device__ __forceinline__ u16 f2bf_rne(float f) {
  unsigned u = __builtin_bit_cast(unsigned, f);
  u += 0x7fffu + ((u >> 16) & 1u);
  return (u16)(u >> 16);
}
__device__ __forceinline__ u16 f2bf_fast(float f) {  // round-half-up
  unsigned u = __builtin_bit_cast(unsigned, f);
  u += 0x8000u;
  return (u16)(u >> 16);
}
__device__ __forceinline__ bf16x8 ld8(const u16* p) {
  return __builtin_bit_cast(bf16x8, *(const u16x8*)p);
}

#define COEF 0.1803368801111204f  // (1/8) * log2(e), folded into Q conversion

// ---------------- prep: Kc = bf16 [K|Kp] concat; Vt = bf16 V-transposed ----
__global__ __launch_bounds__(256)
void prep_kernel(const float* __restrict__ K, const float* __restrict__ V,
                 const float* __restrict__ Kp,
                 u16* __restrict__ Kc, u16* __restrict__ Vt) {
  __shared__ float Ls[64][65];
  int b = blockIdx.x;
  if (b < 4096) {
    int t = b * 256 + threadIdx.x;          // 1,048,576 threads x 8 elems
    int col8 = (t & 15) * 8;
    int s    = (t >> 4) & 2047;
    int bh   = t >> 15;
    const float* src = (col8 < 64) ? (K  + ((size_t)bh * S_ + s) * D_ + col8)
                                   : (Kp + ((size_t)bh * S_ + s) * D_ + (col8 - 64));
    float4 v0 = *(const float4*)src;
    float4 v1 = *(const float4*)(src + 4);
    u16x8 w;
    w[0] = f2bf_rne(v0.x); w[1] = f2bf_rne(v0.y); w[2] = f2bf_rne(v0.z); w[3] = f2bf_rne(v0.w);
    w[4] = f2bf_rne(v1.x); w[5] = f2bf_rne(v1.y); w[6] = f2bf_rne(v1.z); w[7] = f2bf_rne(v1.w);
    *(u16x8*)(Kc + ((size_t)bh * S_ + s) * DQK + col8) = w;
  } else {
    int id = b - 4096;
    int bh = id >> 5, kt = id & 31;
    int tid = threadIdx.x;
    #pragma unroll
    for (int it = 0; it < 4; ++it) {
      int i = it * 256 + tid;
      int kv = i >> 4, dg = (i & 15) * 4;
      float4 v = *(const float4*)(V + ((size_t)bh * S_ + kt * 64 + kv) * D_ + dg);
      Ls[kv][dg + 0] = v.x; Ls[kv][dg + 1] = v.y;
      Ls[kv][dg + 2] = v.z; Ls[kv][dg + 3] = v.w;
    }
    __syncthreads();
    int d = tid >> 2, kvg = (tid & 3) * 16;
    u16x8 w0, w1;
    #pragma unroll
    for (int j = 0; j < 8; ++j) w0[j] = f2bf_rne(Ls[kvg + j][d]);
    #pragma unroll
    for (int j = 0; j < 8; ++j) w1[j] = f2bf_rne(Ls[kvg + 8 + j][d]);
    u16* dst = Vt + (((size_t)bh * 32 + kt) * 64 + d) * 64 + kvg;
    *(u16x8*)dst = w0;
    *(u16x8*)(dst + 8) = w1;
  }
}

// ---------------- flash-attention main kernel -----------------------------
// Barrier-free K-loop: ak (K) and bv (V) fragments are read DIRECTLY from
// global memory (wave-uniform addresses -> 4-way L1 multicast within the
// block; L2/L3 across blocks). LDS holds only the per-wave Ps roundtrip
// (16,384 B -> residency VGPR-capped, ~4 blocks/CU). No __syncthreads
// anywhere in the loop: no vmcnt drains, waves run free.
template <int SPLIT>
__global__ __launch_bounds__(256, 4)
void fa9_kernel(const float* __restrict__ Q, const float* __restrict__ Qp,
                const u16* __restrict__ Kc, const u16* __restrict__ Vtg,
                float* __restrict__ out, float* __restrict__ Opart,
                float* __restrict__ lpart) {
  __shared__ alignas(16) u16 Ps[128 * 64];   // per-wave slabs, swizzled

  const int tid  = threadIdx.x;
  const int wave = tid >> 6;
  const int lane = tid & 63;
  const int quad = lane >> 4;
  const int l16  = lane & 15;
  const int m0   = wave * 32;

  const int bh = blockIdx.y;
  const int q0 = blockIdx.x * BQ;
  const int kz = SPLIT ? blockIdx.z : 0;
  const int kt_b = SPLIT ? kz * 16 : 0;
  const int kt_e = SPLIT ? kt_b + 16 : 32;

  // ---- Q B-frags in registers, softmax scale folded into the conversion ----
  bf16x8 bq[2][4];
  #pragma unroll
  for (int nq = 0; nq < 2; ++nq)
    #pragma unroll
    for (int ks = 0; ks < 4; ++ks) {
      const float* base = (ks < 2 ? Q : Qp)
          + ((size_t)bh * S_ + q0 + m0 + nq * 16 + l16) * D_ + (ks & 1) * 32 + quad * 8;
      float4 v0 = *(const float4*)base;
      float4 v1 = *(const float4*)(base + 4);
      u16x8 w;
      w[0] = f2bf_rne(v0.x * COEF); w[1] = f2bf_rne(v0.y * COEF);
      w[2] = f2bf_rne(v0.z * COEF); w[3] = f2bf_rne(v0.w * COEF);
      w[4] = f2bf_rne(v1.x * COEF); w[5] = f2bf_rne(v1.y * COEF);
      w[6] = f2bf_rne(v1.z * COEF); w[7] = f2bf_rne(v1.w * COEF);
      bq[nq][ks] = __builtin_bit_cast(bf16x8, w);
    }

  f32x4 acc[2][4];
  float l_part[2] = {0.f, 0.f};
  #pragma unroll
  for (int mtq = 0; mtq < 2; ++mtq)
    #pragma unroll
    for (int nt = 0; nt < 4; ++nt) acc[mtq][nt] = (f32x4){0.f, 0.f, 0.f, 0.f};

  // wave-constant fragment bases (per-lane address, advanced per tile)
  const u16* kfrag = Kc + ((size_t)bh * S_ + kt_b * 64 + l16) * DQK + quad * 8;
  const u16* vfrag = Vtg + (((size_t)bh * 32 + kt_b) * 64 + l16) * 64 + quad * 8;

  for (int kt = kt_b; kt < kt_e; ++kt) {
    // ---- S^T = K . Qc^T : ak straight from global (L1/L2 multicast) ----
    #pragma unroll
    for (int mt = 0; mt < 4; ++mt) {
      f32x4 s0 = (f32x4){0.f, 0.f, 0.f, 0.f};
      f32x4 s1 = (f32x4){0.f, 0.f, 0.f, 0.f};
      #pragma unroll
      for (int ks = 0; ks < 4; ++ks) {
        bf16x8 ak = ld8(kfrag + mt * 16 * DQK + ks * 32);
        s0 = __builtin_amdgcn_mfma_f32_16x16x32_bf16(ak, bq[0][ks], s0, 0, 0, 0);
        s1 = __builtin_amdgcn_mfma_f32_16x16x32_bf16(ak, bq[1][ks], s1, 0, 0, 0);
      }
      // C layout: row = kv = quad*4+r, col = q = l16. exp + swizzled b64 P-write.
      u16x4 w0, w1;
      float rs0 = 0.f, rs1 = 0.f;
      #pragma unroll
      for (int r = 0; r < 4; ++r) {
        float p0 = exp2f(s0[r]);
        float p1 = exp2f(s1[r]);
        w0[r] = f2bf_fast(p0); w1[r] = f2bf_fast(p1);
        rs0 += p0; rs1 += p1;
      }
      l_part[0] += rs0; l_part[1] += rs1;
      const int chs = ((mt * 2 + (quad >> 1)) ^ (l16 & 7)) << 3;
      const int sub = (quad & 1) << 2;
      *(u16x4*)&Ps[((m0 + l16) << 6) + chs + sub]      = w0;
      *(u16x4*)&Ps[((m0 + 16 + l16) << 6) + chs + sub] = w1;
    }

    // ---- O += P . V : pa from own-wave Ps slab (lgkm-ordered), bv global --
    bf16x8 pa[2][2];
    #pragma unroll
    for (int mtq = 0; mtq < 2; ++mtq)
      #pragma unroll
      for (int ks = 0; ks < 2; ++ks)
        pa[mtq][ks] = ld8(&Ps[((m0 + mtq * 16 + l16) << 6) + (((ks * 4 + quad) ^ (l16 & 7)) << 3)]);
    #pragma unroll
    for (int ntd = 0; ntd < 4; ++ntd) {
      #pragma unroll
      for (int ks = 0; ks < 2; ++ks) {
        bf16x8 bv = ld8(vfrag + ntd * 16 * 64 + ks * 32);
        acc[0][ntd] = __builtin_amdgcn_mfma_f32_16x16x32_bf16(pa[0][ks], bv, acc[0][ntd], 0, 0, 0);
        acc[1][ntd] = __builtin_amdgcn_mfma_f32_16x16x32_bf16(pa[1][ks], bv, acc[1][ntd], 0, 0, 0);
      }
    }

    kfrag += 64 * DQK;   // next kv tile
    vfrag += 64 * 64;
  }

  // ---- epilogue ----
  float lsum[2];
  #pragma unroll
  for (int nq = 0; nq < 2; ++nq) {
    float v = l_part[nq];
    v += __shfl_xor(v, 16);
    v += __shfl_xor(v, 32);
    lsum[nq] = v;  // lane holds l for q = nq*16 + l16 (this block's kv range)
  }

  if (SPLIT) {
    #pragma unroll
    for (int mtq = 0; mtq < 2; ++mtq)
      #pragma unroll
      for (int r = 0; r < 4; ++r) {
        size_t rowb = ((size_t)kz * 65536 + (size_t)bh * S_
                       + q0 + m0 + mtq * 16 + quad * 4 + r) * D_;
        #pragma unroll
        for (int ntd = 0; ntd < 4; ++ntd)
          Opart[rowb + ntd * 16 + l16] = acc[mtq][ntd][r];
      }
    if (quad == 0) {
      #pragma unroll
      for (int nq = 0; nq < 2; ++nq)
        lpart[(size_t)kz * 65536 + (size_t)bh * S_ + q0 + m0 + nq * 16 + l16] = lsum[nq];
    }
  } else {
    #pragma unroll
    for (int mtq = 0; mtq < 2; ++mtq)
      #pragma unroll
      for (int r = 0; r < 4; ++r) {
        float inv = 1.0f / __shfl(lsum[mtq], quad * 4 + r);
        size_t rowb = ((size_t)bh * S_ + q0 + m0 + mtq * 16 + quad * 4 + r) * D_;
        #pragma unroll
        for (int ntd = 0; ntd < 4; ++ntd)
          out[rowb + ntd * 16 + l16] = acc[mtq][ntd][r] * inv;
      }
  }
}

// ---------------- combine: out = (O0 + O1) / (l0 + l1) --------------------
__global__ __launch_bounds__(256)
void combine_kernel(const float* __restrict__ Opart, const float* __restrict__ lpart,
                    float* __restrict__ out) {
  int t = blockIdx.x * 256 + threadIdx.x;   // 1,048,576 threads
  int row = t >> 4;
  int d4  = (t & 15) * 4;
  const size_t NO = (size_t)65536 * D_;
  float4 o0 = *(const float4*)(Opart + (size_t)row * D_ + d4);
  float4 o1 = *(const float4*)(Opart + NO + (size_t)row * D_ + d4);
  float inv = 1.0f / (lpart[row] + lpart[65536 + row]);
  float4 o;
  o.x = (o0.x + o1.x) * inv; o.y = (o0.y + o1.y) * inv;
  o.z = (o0.z + o1.z) * inv; o.w = (o0.w + o1.w) * inv;
  *(float4*)(out + (size_t)row * D_ + d4) = o;
}

extern "C" void kernel_launch(void* const* d_in, const int* in_sizes, int n_in,
                              void* d_out, int out_size, void* d_ws, size_t ws_size,
                              hipStream_t stream) {
  const float* Q  = (const float*)d_in[0];
  const float* K  = (const float*)d_in[1];
  const float* V  = (const float*)d_in[2];
  const float* Qp = (const float*)d_in[3];
  const float* Kp = (const float*)d_in[4];
  float* out = (float*)d_out;

  const size_t nKc = (size_t)BH_ * S_ * DQK;   // 8.39M u16
  const size_t nVt = (size_t)BH_ * S_ * D_;    // 4.19M u16
  const size_t nO1 = (size_t)65536 * D_;       // per-split O partial (f32)
  const size_t need2 = 2 * (nO1 + 65536) * 4 + (nKc + nVt) * 2;  // ~59.3 MB

  if (ws_size >= need2) {
    float* Opart = (float*)d_ws;
    float* lpart = Opart + 2 * nO1;
    u16* Kc = (u16*)(lpart + 2 * 65536);
    u16* Vt = Kc + nKc;
    prep_kernel<<<dim3(4096 + 1024), dim3(256), 0, stream>>>(K, V, Kp, Kc, Vt);
    fa9_kernel<1><<<dim3(S_ / BQ, BH_, 2), dim3(256), 0, stream>>>(Q, Qp, Kc, Vt, nullptr, Opart, lpart);
    combine_kernel<<<dim3(4096), dim3(256), 0, stream>>>(Opart, lpart, out);
  } else {
    u16* Kc = (u16*)d_ws;
    u16* Vt = Kc + nKc;
    prep_kernel<<<dim3(4096 + 1024), dim3(256), 0, stream>>>(K, V, Kp, Kc, Vt);
    fa9_kernel<0><<<dim3(S_ / BQ, BH_, 1), dim3(256), 0, stream>>>(Q, Qp, Kc, Vt, out, nullptr, nullptr);
  }
}